// Round 11
// baseline (392.034 us; speedup 1.0000x reference)
//
#include <hip/hip_runtime.h>

// GraphAttention: B=4, N=2048, F=256, H=8, F_=64; out [B, N, 512].
// 3 dispatches:
//  k_mask_conv: A->bitmask (+init maxn); X,W->bf16 (extra blocks).
//  k_gemm1    : h=X@W (MFMA, h_t transposed) + fused epilogue: att_s,
//               E=exp(att_n), E5=exp(0.2*att_n), per-bh max(att_n).
//  k_attn_av  : fused masked softmax @ h. Block = 32 rows x 4 waves; each
//               wave covers a 512-wide j-quarter for the SAME rows (in-block
//               j-split -> 8192 waves, no global atomics), partials reduced
//               via LDS at the end. Table-based P (no exp in hot loop):
//               p = (E>exp(-s) ? exp(s-c)*E : exp(0.2s-c)*E5) * maskbit,
//               c = leaky(s+maxn) >= row max (softmax shift-invariant).
//               l via ones-MFMA; trunc pack (bias cancels in l).
// Input dtype detected from A[0][0] (self-loop: fp32 word == 1.0f).

constexpr int GN  = 2048;
constexpr int GHF = 512;

using sh8    = __attribute__((ext_vector_type(8))) short;          // 8 bf16
using us4g   = __attribute__((ext_vector_type(4))) unsigned short;
using f32x4g = __attribute__((ext_vector_type(4))) float;
using i32x4g = __attribute__((ext_vector_type(4))) int;

__device__ inline float gat_bf2f(unsigned short u) {
    union { unsigned int i; float f; } c; c.i = ((unsigned int)u) << 16; return c.f;
}
__device__ inline unsigned short gat_f2bf(float f) {
    union { float f; unsigned int i; } c; c.f = f;
    return (unsigned short)((c.i + 0x7fffu + ((c.i >> 16) & 1u)) >> 16); // RNE
}
__device__ inline int gat_isf32(const float* __restrict__ Aw) {
    float a = Aw[0];
    return (a == 0.0f) || (a == 1.0f);
}
__device__ inline unsigned int gat_enc(float f) {
    union { float f; unsigned int u; } c; c.f = f;
    return (c.u & 0x80000000u) ? ~c.u : (c.u | 0x80000000u);
}
__device__ inline float gat_dec(unsigned int e) {
    union { float f; unsigned int u; } c;
    c.u = (e & 0x80000000u) ? (e & 0x7fffffffu) : ~e;
    return c.f;
}

__global__ void GraphAttention_62981400429165_kernel() {}

// ---------------- workspace layout (bytes) ----------------
constexpr size_t OFF_HT   = 256;                       // h_t bf16       8 MB
constexpr size_t OFF_ATTS = OFF_HT   + 8388608;        // att_s f32    256 KB
constexpr size_t OFF_E    = OFF_ATTS + 262144;         // exp(n)       256 KB
constexpr size_t OFF_E5   = OFF_E    + 262144;         // exp(.2n)     256 KB
constexpr size_t OFF_MASK = OFF_E5   + 262144;         // bitmask        2 MB
constexpr size_t OFF_MAXN = OFF_MASK + 2097152;        // 32 u32
constexpr size_t OFF_XC   = OFF_MAXN + 256;            // X bf16         4 MB
constexpr size_t OFF_WC   = OFF_XC   + 4194304;        // W bf16       256 KB

// --------------------------------------------------------------------------
// k_mask_conv: blocks 0..65535: A->mask (+block 0 inits maxn).
// 65536..73727: X->bf16. 73728..74239: W->bf16.
// --------------------------------------------------------------------------
__global__ __launch_bounds__(256) void k_mask_conv(const void* __restrict__ Araw,
                                                   const void* __restrict__ Xraw,
                                                   const void* __restrict__ Wraw,
                                                   unsigned long long* __restrict__ mask,
                                                   unsigned int* __restrict__ maxn_enc,
                                                   unsigned short* __restrict__ Xc,
                                                   unsigned short* __restrict__ Wc) {
    int tid = threadIdx.x, blk = blockIdx.x;
    int isf = gat_isf32((const float*)Araw);
    if (blk < 65536) {
        if (blk == 0 && tid < 32) maxn_enc[tid] = 0u;
        size_t idx = (size_t)blk * 256 + tid;
        int nz;
        if (isf) nz = (((const float*)Araw)[idx] != 0.0f);
        else     nz = (((const unsigned short*)Araw)[idx] != 0);
        unsigned long long bal = __ballot(nz);
        if ((tid & 63) == 0) mask[idx >> 6] = bal;
    } else if (blk < 73728) {
        int i = (blk - 65536) * 256 + tid;
        Xc[i] = isf ? gat_f2bf(((const float*)Xraw)[i]) : ((const unsigned short*)Xraw)[i];
    } else {
        int i = (blk - 73728) * 256 + tid;
        Wc[i] = isf ? gat_f2bf(((const float*)Wraw)[i]) : ((const unsigned short*)Wraw)[i];
    }
}

// --------------------------------------------------------------------------
// k_gemm1: h = X @ W per (b,h) + fused att epilogue (att_s, E, E5, maxn).
// grid 256 (bh*8+it) x 256 (4 waves x 64 rows).
// --------------------------------------------------------------------------
constexpr int LDW = 264;
__global__ __launch_bounds__(256) void k_gemm1(const unsigned short* __restrict__ Xc,
                                               const unsigned short* __restrict__ Wc,
                                               const void* __restrict__ aSraw,
                                               const void* __restrict__ aNraw,
                                               const float* __restrict__ Aw,
                                               unsigned short* __restrict__ h_t,
                                               float* __restrict__ att_s,
                                               float* __restrict__ Eb,
                                               float* __restrict__ E5b,
                                               unsigned int* __restrict__ maxn_enc) {
    int blk = blockIdx.x;
    int bh = blk >> 3, it = blk & 7;
    int b = bh >> 3, hh = bh & 7;
    int isf = gat_isf32(Aw);
    __shared__ unsigned short Wt[64 * LDW];
    for (int idx = threadIdx.x; idx < 256 * 64; idx += 256) {
        int k = idx >> 6, col = idx & 63;
        Wt[col * LDW + k] = Wc[(hh * 256 + k) * 64 + col];
    }
    __syncthreads();
#if defined(__gfx950__)
    int wave = threadIdx.x >> 6, lane = threadIdx.x & 63;
    int lrw = lane & 15, quad = lane >> 4;
    int row0 = it * 256 + wave * 64;
    f32x4g acc[4][4] = {};
    for (int k0 = 0; k0 < 256; k0 += 32) {
        sh8 a[4], w[4];
        for (int rt = 0; rt < 4; rt++)
            a[rt] = *(const sh8*)&Xc[((size_t)(b * GN) + row0 + rt * 16 + lrw) * 256 + k0 + quad * 8];
        for (int ct = 0; ct < 4; ct++)
            w[ct] = *(const sh8*)&Wt[(ct * 16 + lrw) * LDW + k0 + quad * 8];
        for (int rt = 0; rt < 4; rt++)
            for (int ct = 0; ct < 4; ct++)
                acc[rt][ct] = __builtin_amdgcn_mfma_f32_16x16x32_bf16(a[rt], w[ct], acc[rt][ct], 0, 0, 0);
    }
    for (int rt = 0; rt < 4; rt++)
        for (int ct = 0; ct < 4; ct++) {
            int col = ct * 16 + lrw;
            int row = row0 + rt * 16 + quad * 4;
            us4g v;
            v[0] = gat_f2bf(acc[rt][ct][0]);
            v[1] = gat_f2bf(acc[rt][ct][1]);
            v[2] = gat_f2bf(acc[rt][ct][2]);
            v[3] = gat_f2bf(acc[rt][ct][3]);
            *(us4g*)&h_t[((size_t)(bh * 64 + col)) * GN + row] = v;
        }
    // ---- fused att epilogue: att_s, E, E5, maxn ----
    float as_l[4], an_l[4];
    for (int ct = 0; ct < 4; ct++) {
        int col = hh * 64 + ct * 16 + lrw;
        as_l[ct] = isf ? ((const float*)aSraw)[col] : gat_bf2f(((const unsigned short*)aSraw)[col]);
        an_l[ct] = isf ? ((const float*)aNraw)[col] : gat_bf2f(((const unsigned short*)aNraw)[col]);
    }
    float wmax = -3e38f;
    for (int rt = 0; rt < 4; rt++)
        for (int r = 0; r < 4; r++) {
            float ps = acc[rt][0][r] * as_l[0] + acc[rt][1][r] * as_l[1]
                     + acc[rt][2][r] * as_l[2] + acc[rt][3][r] * as_l[3];
            float pn = acc[rt][0][r] * an_l[0] + acc[rt][1][r] * an_l[1]
                     + acc[rt][2][r] * an_l[2] + acc[rt][3][r] * an_l[3];
            for (int off = 1; off < 16; off <<= 1) {
                ps += __shfl_xor(ps, off);
                pn += __shfl_xor(pn, off);
            }
            int row = row0 + rt * 16 + quad * 4 + r;
            if (lrw == 0) {
                att_s[bh * GN + row] = ps;
                Eb[bh * GN + row]  = __expf(pn);
                E5b[bh * GN + row] = __expf(0.2f * pn);
            }
            wmax = fmaxf(wmax, pn);
        }
    wmax = fmaxf(wmax, __shfl_xor(wmax, 16));
    wmax = fmaxf(wmax, __shfl_xor(wmax, 32));
    if (lane == 0) atomicMax(&maxn_enc[bh], gat_enc(wmax));
#else
    int row = it * 256 + threadIdx.x;
    float hrow[64];
    for (int col = 0; col < 64; col++) {
        float s = 0.f;
        for (int k = 0; k < 256; k++)
            s += gat_bf2f(Xc[((size_t)(b * GN) + row) * 256 + k]) * gat_bf2f(Wt[col * LDW + k]);
        hrow[col] = s;
        h_t[((size_t)(bh * 64 + col)) * GN + row] = gat_f2bf(s);
    }
    float ps = 0.f, pn = 0.f;
    for (int col = 0; col < 64; col++) {
        float as = isf ? ((const float*)aSraw)[hh * 64 + col] : gat_bf2f(((const unsigned short*)aSraw)[hh * 64 + col]);
        float an = isf ? ((const float*)aNraw)[hh * 64 + col] : gat_bf2f(((const unsigned short*)aNraw)[hh * 64 + col]);
        ps += hrow[col] * as;
        pn += hrow[col] * an;
    }
    att_s[bh * GN + row] = ps;
    Eb[bh * GN + row]  = __expf(pn);
    E5b[bh * GN + row] = __expf(0.2f * pn);
    atomicMax(&maxn_enc[bh], gat_enc(pn));
#endif
}

// --------------------------------------------------------------------------
// k_attn_av: out = relu( softmax(P) @ h ). grid 2048 (bh = blk&31 for XCD
// locality, it = blk>>5 -> 32 rows), 256 thr = 4 waves. Wave w handles
// j in [w*512, w*512+512) for all 32 rows (2 A-frags). Partials reduced
// through LDS at the end (no atomics). Table-based P, no exp in hot loop.
// --------------------------------------------------------------------------
__global__ __launch_bounds__(256, 6) void k_attn_av(const unsigned int* __restrict__ mask32,
                                                    const unsigned short* __restrict__ h_t,
                                                    const float* __restrict__ att_s,
                                                    const float* __restrict__ Eb,
                                                    const float* __restrict__ E5b,
                                                    const unsigned int* __restrict__ maxn_enc,
                                                    const float* __restrict__ Aw,
                                                    void* __restrict__ outv) {
    int blk = blockIdx.x;
    int bh = blk & 31, it = blk >> 5;
    int b = bh >> 3, hh = bh & 7;
    int i0 = it * 32;
    int tid = threadIdx.x;
    int isf = gat_isf32(Aw);
    float maxn = gat_dec(maxn_enc[bh]);
    const float* Ep  = Eb  + (size_t)bh * GN;
    const float* E5p = E5b + (size_t)bh * GN;
    const unsigned short* hb = h_t + (size_t)bh * 64 * GN;
#if defined(__gfx950__)
    int wave = tid >> 6, lane = tid & 63, lrw = lane & 15, quad = lane >> 4;
    int kq = quad * 8;
    int j0 = wave * 512;                             // this wave's j-quarter
    float k1[2], k2[2], T0[2];
    const unsigned int* mrf[2];
    for (int f = 0; f < 2; f++) {
        int row = i0 + f * 16 + lrw;
        float s = att_s[bh * GN + row];
        float z = s + maxn;
        float c = fmaxf(z, 0.2f * z);                // >= true row max
        k1[f] = __expf(s - c);
        k2[f] = __expf(0.2f * s - c);
        T0[f] = __expf(-s);
        mrf[f] = mask32 + ((size_t)(b * GN) + row) * 64 + wave * 16;
    }
    f32x4g acc[2][4] = {};
    f32x4g accl[2] = {};
    sh8 ones;
#pragma unroll
    for (int e = 0; e < 8; e++) ones[e] = (short)0x3f80;  // bf16 1.0

#pragma unroll 1
    for (int jc = 0; jc < 16; jc++) {
        int jq = j0 + jc * 32 + kq;
        f32x4g eA  = *(const f32x4g*)&Ep[jq];
        f32x4g eB  = *(const f32x4g*)&Ep[jq + 4];
        f32x4g e5A = *(const f32x4g*)&E5p[jq];
        f32x4g e5B = *(const f32x4g*)&E5p[jq + 4];
        sh8 af[2];
#pragma unroll
        for (int f = 0; f < 2; f++) {
            unsigned int w = mrf[f][jc] >> kq;
            unsigned int q[8];
#pragma unroll
            for (int e = 0; e < 8; e++) {
                float Ev  = (e < 4) ? eA[e]  : eB[e - 4];
                float E5v = (e < 4) ? e5A[e] : e5B[e - 4];
                float p = (Ev > T0[f]) ? (k1[f] * Ev) : (k2[f] * E5v);
                p = ((w >> e) & 1u) ? p : 0.0f;
                q[e] = __float_as_uint(p);
            }
            i32x4g fq;
#pragma unroll
            for (int pp = 0; pp < 4; pp++)           // trunc pack (bias cancels in l)
                fq[pp] = (int)((q[2 * pp] >> 16) | (q[2 * pp + 1] & 0xffff0000u));
            af[f] = *(sh8*)&fq;
        }
#pragma unroll
        for (int ct = 0; ct < 4; ct++) {
            sh8 bf = *(const sh8*)&hb[((size_t)(ct * 16 + lrw)) * GN + jq];
            acc[0][ct] = __builtin_amdgcn_mfma_f32_16x16x32_bf16(af[0], bf, acc[0][ct], 0, 0, 0);
            acc[1][ct] = __builtin_amdgcn_mfma_f32_16x16x32_bf16(af[1], bf, acc[1][ct], 0, 0, 0);
        }
        accl[0] = __builtin_amdgcn_mfma_f32_16x16x32_bf16(af[0], ones, accl[0], 0, 0, 0);
        accl[1] = __builtin_amdgcn_mfma_f32_16x16x32_bf16(af[1], ones, accl[1], 0, 0, 0);
    }
    // ---- end-of-kernel reduction across the 4 j-split waves (LDS) ----
    __shared__ float lred[4 * 32];                   // [wave][row32]
    __shared__ float lsum[32];                       // 1/l per row
    __shared__ float red[4 * 2 * 16 * 17];           // [wave][f][r16][c16 pad17]
    if (lrw == 0) {
#pragma unroll
        for (int f = 0; f < 2; f++)
#pragma unroll
            for (int r = 0; r < 4; r++)
                lred[wave * 32 + f * 16 + quad * 4 + r] = accl[f][r];
    }
    __syncthreads();
    if (tid < 32)
        lsum[tid] = 1.0f / (lred[tid] + lred[32 + tid] + lred[64 + tid] + lred[96 + tid]);
    __syncthreads();
    for (int ct = 0; ct < 4; ct++) {
#pragma unroll
        for (int f = 0; f < 2; f++)
#pragma unroll
            for (int r = 0; r < 4; r++)
                red[((wave * 2 + f) * 16 + quad * 4 + r) * 17 + lrw] = acc[f][ct][r];
        __syncthreads();
#pragma unroll
        for (int k = 0; k < 2; k++) {
            int pos = k * 256 + tid;                 // f(1b) r16(4b) c16(4b)
            int f = pos >> 8, r16 = (pos >> 4) & 15, c16 = pos & 15;
            int bse = f * 272 + r16 * 17 + c16;      // 272 = 16*17
            float sum = red[bse] + red[bse + 544] + red[bse + 1088] + red[bse + 1632];
            float v = sum * lsum[f * 16 + r16];
            v = v > 0.f ? v : 0.f;
            int row = i0 + f * 16 + r16;
            size_t o = ((size_t)(b * GN) + row) * GHF + hh * 64 + ct * 16 + c16;
            if (isf) ((float*)outv)[o] = v;
            else     ((unsigned short*)outv)[o] = gat_f2bf(v);
        }
        __syncthreads();
    }
#else
    // correctness-only fallback: thread -> (row = tid>>3, 8-col chunk)
    int row = i0 + (tid >> 3), chh = (tid & 7) * 8;
    const unsigned int* mr = mask32 + ((size_t)(b * GN) + row) * 64;
    float s = att_s[bh * GN + row];
    float z = s + maxn;
    float c = fmaxf(z, 0.2f * z);
    float k1 = __expf(s - c), k2 = __expf(0.2f * s - c), T0 = __expf(-s);
    float l = 0.f;
    float accS[8] = {};
    for (int j = 0; j < GN; j++) {
        if (!((mr[j >> 5] >> (j & 31)) & 1u)) continue;
        float Ev = Ep[j], E5v = E5p[j];
        float p = (Ev > T0) ? (k1 * Ev) : (k2 * E5v);
        union { float f; unsigned int u; } t; t.f = p; t.u &= 0xffff0000u;
        l += t.f;
        for (int cc = 0; cc < 8; cc++)
            accS[cc] += t.f * gat_bf2f(hb[(size_t)(chh + cc) * GN + j]);
    }
    float li = 1.0f / l;
    for (int cc = 0; cc < 8; cc++) {
        float v = accS[cc] * li; v = v > 0.f ? v : 0.f;
        size_t oi = ((size_t)(b * GN) + row) * GHF + hh * 64 + chh + cc;
        if (isf) ((float*)outv)[oi] = v;
        else     ((unsigned short*)outv)[oi] = gat_f2bf(v);
    }
#endif
}

// --------------------------------------------------------------------------
extern "C" void kernel_launch(void* const* d_in, const int* in_sizes, int n_in,
                              void* d_out, int out_size, void* d_ws, size_t ws_size,
                              hipStream_t stream) {
    const void* X  = d_in[0];
    const void* A  = d_in[1];
    const void* W  = d_in[2];
    const void* aS = d_in[3];
    const void* aN = d_in[4];

    char* ws = (char*)d_ws;
    unsigned short* h_t = (unsigned short*)(ws + OFF_HT);
    float* att_s = (float*)(ws + OFF_ATTS);
    float* Eb    = (float*)(ws + OFF_E);
    float* E5b   = (float*)(ws + OFF_E5);
    unsigned long long* mask = (unsigned long long*)(ws + OFF_MASK);
    unsigned int* maxn_enc = (unsigned int*)(ws + OFF_MAXN);
    unsigned short* Xc = (unsigned short*)(ws + OFF_XC);
    unsigned short* Wc = (unsigned short*)(ws + OFF_WC);

    k_mask_conv<<<74240, 256, 0, stream>>>(A, X, W, mask, maxn_enc, Xc, Wc);
    k_gemm1<<<256, 256, 0, stream>>>(Xc, Wc, aS, aN, (const float*)A,
                                     h_t, att_s, Eb, E5b, maxn_enc);
    k_attn_av<<<2048, 256, 0, stream>>>((const unsigned int*)mask, h_t,
                                        att_s, Eb, E5b, maxn_enc,
                                        (const float*)A, d_out);
}

// Round 12
// 246.602 us; speedup vs baseline: 1.5897x; 1.5897x over previous
//
#include <hip/hip_runtime.h>

// GraphAttention: B=4, N=2048, F=256, H=8, F_=64; out [B, N, 512].
// 3 dispatches:
//  k_mask_conv: A->bitmask (+init maxn); X,W->bf16 (extra blocks).
//  k_gemm1    : h=X@W (MFMA, h_t transposed) + fused epilogue: att_s,
//               E=exp(att_n), E5=exp(0.2*att_n), per-bh max(att_n).
//  k_attn_av  : fused masked softmax @ h. Block = 128 thr = 2 waves; both
//               waves own the same 32 rows (2 A-frags), each covers a
//               1024-wide j-half -> 4096 waves (4/SIMD), no global atomics;
//               partials reduced via 4.6KB LDS at the end. Table-based P
//               (no exp in hot loop): p = (E>exp(-s) ? exp(s-c)*E
//               : exp(0.2s-c)*E5) * maskbit, c = leaky(s+maxn) >= row max.
//               l via ones-MFMA; trunc pack (bias cancels in l).
// Register budget note: __launch_bounds__(128,4) -> 128 VGPR cap; per-wave
// live state ~90 regs. (256,6) in a previous round forced 40 VGPR -> scratch
// spills -> 378MB HBM traffic. Do not tighten the cap below ~100.
// Input dtype detected from A[0][0] (self-loop: fp32 word == 1.0f).

constexpr int GN  = 2048;
constexpr int GHF = 512;

using sh8    = __attribute__((ext_vector_type(8))) short;          // 8 bf16
using us4g   = __attribute__((ext_vector_type(4))) unsigned short;
using f32x4g = __attribute__((ext_vector_type(4))) float;
using i32x4g = __attribute__((ext_vector_type(4))) int;

__device__ inline float gat_bf2f(unsigned short u) {
    union { unsigned int i; float f; } c; c.i = ((unsigned int)u) << 16; return c.f;
}
__device__ inline unsigned short gat_f2bf(float f) {
    union { float f; unsigned int i; } c; c.f = f;
    return (unsigned short)((c.i + 0x7fffu + ((c.i >> 16) & 1u)) >> 16); // RNE
}
__device__ inline int gat_isf32(const float* __restrict__ Aw) {
    float a = Aw[0];
    return (a == 0.0f) || (a == 1.0f);
}
__device__ inline unsigned int gat_enc(float f) {
    union { float f; unsigned int u; } c; c.f = f;
    return (c.u & 0x80000000u) ? ~c.u : (c.u | 0x80000000u);
}
__device__ inline float gat_dec(unsigned int e) {
    union { float f; unsigned int u; } c;
    c.u = (e & 0x80000000u) ? (e & 0x7fffffffu) : ~e;
    return c.f;
}

__global__ void GraphAttention_62981400429165_kernel() {}

// ---------------- workspace layout (bytes) ----------------
constexpr size_t OFF_HT   = 256;                       // h_t bf16       8 MB
constexpr size_t OFF_ATTS = OFF_HT   + 8388608;        // att_s f32    256 KB
constexpr size_t OFF_E    = OFF_ATTS + 262144;         // exp(n)       256 KB
constexpr size_t OFF_E5   = OFF_E    + 262144;         // exp(.2n)     256 KB
constexpr size_t OFF_MASK = OFF_E5   + 262144;         // bitmask        2 MB
constexpr size_t OFF_MAXN = OFF_MASK + 2097152;        // 32 u32
constexpr size_t OFF_XC   = OFF_MAXN + 256;            // X bf16         4 MB
constexpr size_t OFF_WC   = OFF_XC   + 4194304;        // W bf16       256 KB

// --------------------------------------------------------------------------
// k_mask_conv: blocks 0..65535: A->mask (+block 0 inits maxn).
// 65536..73727: X->bf16. 73728..74239: W->bf16.
// --------------------------------------------------------------------------
__global__ __launch_bounds__(256) void k_mask_conv(const void* __restrict__ Araw,
                                                   const void* __restrict__ Xraw,
                                                   const void* __restrict__ Wraw,
                                                   unsigned long long* __restrict__ mask,
                                                   unsigned int* __restrict__ maxn_enc,
                                                   unsigned short* __restrict__ Xc,
                                                   unsigned short* __restrict__ Wc) {
    int tid = threadIdx.x, blk = blockIdx.x;
    int isf = gat_isf32((const float*)Araw);
    if (blk < 65536) {
        if (blk == 0 && tid < 32) maxn_enc[tid] = 0u;
        size_t idx = (size_t)blk * 256 + tid;
        int nz;
        if (isf) nz = (((const float*)Araw)[idx] != 0.0f);
        else     nz = (((const unsigned short*)Araw)[idx] != 0);
        unsigned long long bal = __ballot(nz);
        if ((tid & 63) == 0) mask[idx >> 6] = bal;
    } else if (blk < 73728) {
        int i = (blk - 65536) * 256 + tid;
        Xc[i] = isf ? gat_f2bf(((const float*)Xraw)[i]) : ((const unsigned short*)Xraw)[i];
    } else {
        int i = (blk - 73728) * 256 + tid;
        Wc[i] = isf ? gat_f2bf(((const float*)Wraw)[i]) : ((const unsigned short*)Wraw)[i];
    }
}

// --------------------------------------------------------------------------
// k_gemm1: h = X @ W per (b,h) + fused att epilogue (att_s, E, E5, maxn).
// grid 256 (bh*8+it) x 256 (4 waves x 64 rows).
// --------------------------------------------------------------------------
constexpr int LDW = 264;
__global__ __launch_bounds__(256) void k_gemm1(const unsigned short* __restrict__ Xc,
                                               const unsigned short* __restrict__ Wc,
                                               const void* __restrict__ aSraw,
                                               const void* __restrict__ aNraw,
                                               const float* __restrict__ Aw,
                                               unsigned short* __restrict__ h_t,
                                               float* __restrict__ att_s,
                                               float* __restrict__ Eb,
                                               float* __restrict__ E5b,
                                               unsigned int* __restrict__ maxn_enc) {
    int blk = blockIdx.x;
    int bh = blk >> 3, it = blk & 7;
    int b = bh >> 3, hh = bh & 7;
    int isf = gat_isf32(Aw);
    __shared__ unsigned short Wt[64 * LDW];
    for (int idx = threadIdx.x; idx < 256 * 64; idx += 256) {
        int k = idx >> 6, col = idx & 63;
        Wt[col * LDW + k] = Wc[(hh * 256 + k) * 64 + col];
    }
    __syncthreads();
#if defined(__gfx950__)
    int wave = threadIdx.x >> 6, lane = threadIdx.x & 63;
    int lrw = lane & 15, quad = lane >> 4;
    int row0 = it * 256 + wave * 64;
    f32x4g acc[4][4] = {};
    for (int k0 = 0; k0 < 256; k0 += 32) {
        sh8 a[4], w[4];
        for (int rt = 0; rt < 4; rt++)
            a[rt] = *(const sh8*)&Xc[((size_t)(b * GN) + row0 + rt * 16 + lrw) * 256 + k0 + quad * 8];
        for (int ct = 0; ct < 4; ct++)
            w[ct] = *(const sh8*)&Wt[(ct * 16 + lrw) * LDW + k0 + quad * 8];
        for (int rt = 0; rt < 4; rt++)
            for (int ct = 0; ct < 4; ct++)
                acc[rt][ct] = __builtin_amdgcn_mfma_f32_16x16x32_bf16(a[rt], w[ct], acc[rt][ct], 0, 0, 0);
    }
    for (int rt = 0; rt < 4; rt++)
        for (int ct = 0; ct < 4; ct++) {
            int col = ct * 16 + lrw;
            int row = row0 + rt * 16 + quad * 4;
            us4g v;
            v[0] = gat_f2bf(acc[rt][ct][0]);
            v[1] = gat_f2bf(acc[rt][ct][1]);
            v[2] = gat_f2bf(acc[rt][ct][2]);
            v[3] = gat_f2bf(acc[rt][ct][3]);
            *(us4g*)&h_t[((size_t)(bh * 64 + col)) * GN + row] = v;
        }
    // ---- fused att epilogue: att_s, E, E5, maxn ----
    float as_l[4], an_l[4];
    for (int ct = 0; ct < 4; ct++) {
        int col = hh * 64 + ct * 16 + lrw;
        as_l[ct] = isf ? ((const float*)aSraw)[col] : gat_bf2f(((const unsigned short*)aSraw)[col]);
        an_l[ct] = isf ? ((const float*)aNraw)[col] : gat_bf2f(((const unsigned short*)aNraw)[col]);
    }
    float wmax = -3e38f;
    for (int rt = 0; rt < 4; rt++)
        for (int r = 0; r < 4; r++) {
            float ps = acc[rt][0][r] * as_l[0] + acc[rt][1][r] * as_l[1]
                     + acc[rt][2][r] * as_l[2] + acc[rt][3][r] * as_l[3];
            float pn = acc[rt][0][r] * an_l[0] + acc[rt][1][r] * an_l[1]
                     + acc[rt][2][r] * an_l[2] + acc[rt][3][r] * an_l[3];
            for (int off = 1; off < 16; off <<= 1) {
                ps += __shfl_xor(ps, off);
                pn += __shfl_xor(pn, off);
            }
            int row = row0 + rt * 16 + quad * 4 + r;
            if (lrw == 0) {
                att_s[bh * GN + row] = ps;
                Eb[bh * GN + row]  = __expf(pn);
                E5b[bh * GN + row] = __expf(0.2f * pn);
            }
            wmax = fmaxf(wmax, pn);
        }
    wmax = fmaxf(wmax, __shfl_xor(wmax, 16));
    wmax = fmaxf(wmax, __shfl_xor(wmax, 32));
    if (lane == 0) atomicMax(&maxn_enc[bh], gat_enc(wmax));
#else
    int row = it * 256 + threadIdx.x;
    float hrow[64];
    for (int col = 0; col < 64; col++) {
        float s = 0.f;
        for (int k = 0; k < 256; k++)
            s += gat_bf2f(Xc[((size_t)(b * GN) + row) * 256 + k]) * gat_bf2f(Wt[col * LDW + k]);
        hrow[col] = s;
        h_t[((size_t)(bh * 64 + col)) * GN + row] = gat_f2bf(s);
    }
    float ps = 0.f, pn = 0.f;
    for (int col = 0; col < 64; col++) {
        float as = isf ? ((const float*)aSraw)[hh * 64 + col] : gat_bf2f(((const unsigned short*)aSraw)[hh * 64 + col]);
        float an = isf ? ((const float*)aNraw)[hh * 64 + col] : gat_bf2f(((const unsigned short*)aNraw)[hh * 64 + col]);
        ps += hrow[col] * as;
        pn += hrow[col] * an;
    }
    att_s[bh * GN + row] = ps;
    Eb[bh * GN + row]  = __expf(pn);
    E5b[bh * GN + row] = __expf(0.2f * pn);
    atomicMax(&maxn_enc[bh], gat_enc(pn));
#endif
}

// --------------------------------------------------------------------------
// k_attn_av: out = relu( softmax(P) @ h ). grid 2048 (bh = blk&31 for XCD
// locality, it = blk>>5 -> 32 rows), 128 thr = 2 waves. Wave w handles
// j in [w*1024, w*1024+1024) for the SAME 32 rows (2 A-frags). Partials
// reduced through LDS at the end (no atomics). Table-based P, no exp in
// the hot loop.
// --------------------------------------------------------------------------
__global__ __launch_bounds__(128, 4) void k_attn_av(const unsigned int* __restrict__ mask32,
                                                    const unsigned short* __restrict__ h_t,
                                                    const float* __restrict__ att_s,
                                                    const float* __restrict__ Eb,
                                                    const float* __restrict__ E5b,
                                                    const unsigned int* __restrict__ maxn_enc,
                                                    const float* __restrict__ Aw,
                                                    void* __restrict__ outv) {
    int blk = blockIdx.x;
    int bh = blk & 31, it = blk >> 5;
    int b = bh >> 3, hh = bh & 7;
    int i0 = it * 32;
    int tid = threadIdx.x;
    int isf = gat_isf32(Aw);
    float maxn = gat_dec(maxn_enc[bh]);
    const float* Ep  = Eb  + (size_t)bh * GN;
    const float* E5p = E5b + (size_t)bh * GN;
    const unsigned short* hb = h_t + (size_t)bh * 64 * GN;
#if defined(__gfx950__)
    int wave = tid >> 6, lane = tid & 63, lrw = lane & 15, quad = lane >> 4;
    int kq = quad * 8;
    int j0 = wave * 1024;                            // this wave's j-half
    float k1[2], k2[2], T0[2];
    const unsigned int* mrf[2];
    for (int f = 0; f < 2; f++) {
        int row = i0 + f * 16 + lrw;
        float s = att_s[bh * GN + row];
        float z = s + maxn;
        float c = fmaxf(z, 0.2f * z);                // >= true row max
        k1[f] = __expf(s - c);
        k2[f] = __expf(0.2f * s - c);
        T0[f] = __expf(-s);
        mrf[f] = mask32 + ((size_t)(b * GN) + row) * 64 + wave * 32;
    }
    f32x4g acc[2][4] = {};
    f32x4g accl[2] = {};
    sh8 ones;
#pragma unroll
    for (int e = 0; e < 8; e++) ones[e] = (short)0x3f80;  // bf16 1.0

    for (int jc = 0; jc < 32; jc++) {
        int jq = j0 + jc * 32 + kq;
        f32x4g eA  = *(const f32x4g*)&Ep[jq];
        f32x4g eB  = *(const f32x4g*)&Ep[jq + 4];
        f32x4g e5A = *(const f32x4g*)&E5p[jq];
        f32x4g e5B = *(const f32x4g*)&E5p[jq + 4];
        sh8 af[2];
#pragma unroll
        for (int f = 0; f < 2; f++) {
            unsigned int w = mrf[f][jc] >> kq;
            unsigned int q[8];
#pragma unroll
            for (int e = 0; e < 8; e++) {
                float Ev  = (e < 4) ? eA[e]  : eB[e - 4];
                float E5v = (e < 4) ? e5A[e] : e5B[e - 4];
                float p = (Ev > T0[f]) ? (k1[f] * Ev) : (k2[f] * E5v);
                p = ((w >> e) & 1u) ? p : 0.0f;
                q[e] = __float_as_uint(p);
            }
            i32x4g fq;
#pragma unroll
            for (int pp = 0; pp < 4; pp++)           // trunc pack (bias cancels in l)
                fq[pp] = (int)((q[2 * pp] >> 16) | (q[2 * pp + 1] & 0xffff0000u));
            af[f] = *(sh8*)&fq;
        }
#pragma unroll
        for (int ct = 0; ct < 4; ct++) {
            sh8 bf = *(const sh8*)&hb[((size_t)(ct * 16 + lrw)) * GN + jq];
            acc[0][ct] = __builtin_amdgcn_mfma_f32_16x16x32_bf16(af[0], bf, acc[0][ct], 0, 0, 0);
            acc[1][ct] = __builtin_amdgcn_mfma_f32_16x16x32_bf16(af[1], bf, acc[1][ct], 0, 0, 0);
        }
        accl[0] = __builtin_amdgcn_mfma_f32_16x16x32_bf16(af[0], ones, accl[0], 0, 0, 0);
        accl[1] = __builtin_amdgcn_mfma_f32_16x16x32_bf16(af[1], ones, accl[1], 0, 0, 0);
    }
    // ---- end-of-kernel reduction across the 2 j-half waves (LDS) ----
    __shared__ float lred[2 * 32];                   // [wave][row32]
    __shared__ float lsum[32];                       // 1/l per row
    __shared__ float red[2 * 2 * 16 * 17];           // [wave][f][r16][c16 pad17]
    if (lrw == 0) {
#pragma unroll
        for (int f = 0; f < 2; f++)
#pragma unroll
            for (int r = 0; r < 4; r++)
                lred[wave * 32 + f * 16 + quad * 4 + r] = accl[f][r];
    }
    __syncthreads();
    if (tid < 32)
        lsum[tid] = 1.0f / (lred[tid] + lred[32 + tid]);
    __syncthreads();
    for (int ct = 0; ct < 4; ct++) {
#pragma unroll
        for (int f = 0; f < 2; f++)
#pragma unroll
            for (int r = 0; r < 4; r++)
                red[wave * 544 + f * 272 + (quad * 4 + r) * 17 + lrw] = acc[f][ct][r];
        __syncthreads();
#pragma unroll
        for (int k = 0; k < 4; k++) {
            int pos = k * 128 + tid;                 // [0,512): f(1b) r16(4b) c16(4b)
            int f = pos >> 8, r16 = (pos >> 4) & 15, c16 = pos & 15;
            int bse = f * 272 + r16 * 17 + c16;
            float sum = red[bse] + red[bse + 544];
            float v = sum * lsum[f * 16 + r16];
            v = v > 0.f ? v : 0.f;
            int row = i0 + f * 16 + r16;
            size_t o = ((size_t)(b * GN) + row) * GHF + hh * 64 + ct * 16 + c16;
            if (isf) ((float*)outv)[o] = v;
            else     ((unsigned short*)outv)[o] = gat_f2bf(v);
        }
        __syncthreads();
    }
#else
    // correctness-only fallback: thread -> (row = tid>>2, 16-col quarter)
    int row = i0 + (tid >> 2), chh = (tid & 3) * 16;
    const unsigned int* mr = mask32 + ((size_t)(b * GN) + row) * 64;
    float s = att_s[bh * GN + row];
    float z = s + maxn;
    float c = fmaxf(z, 0.2f * z);
    float k1 = __expf(s - c), k2 = __expf(0.2f * s - c), T0 = __expf(-s);
    float l = 0.f;
    float accS[16] = {};
    for (int j = 0; j < GN; j++) {
        if (!((mr[j >> 5] >> (j & 31)) & 1u)) continue;
        float Ev = Ep[j], E5v = E5p[j];
        float p = (Ev > T0) ? (k1 * Ev) : (k2 * E5v);
        union { float f; unsigned int u; } t; t.f = p; t.u &= 0xffff0000u;
        l += t.f;
        for (int cc = 0; cc < 16; cc++)
            accS[cc] += t.f * gat_bf2f(hb[(size_t)(chh + cc) * GN + j]);
    }
    float li = 1.0f / l;
    for (int cc = 0; cc < 16; cc++) {
        float v = accS[cc] * li; v = v > 0.f ? v : 0.f;
        size_t oi = ((size_t)(b * GN) + row) * GHF + hh * 64 + chh + cc;
        if (isf) ((float*)outv)[oi] = v;
        else     ((unsigned short*)outv)[oi] = gat_f2bf(v);
    }
#endif
}

// --------------------------------------------------------------------------
extern "C" void kernel_launch(void* const* d_in, const int* in_sizes, int n_in,
                              void* d_out, int out_size, void* d_ws, size_t ws_size,
                              hipStream_t stream) {
    const void* X  = d_in[0];
    const void* A  = d_in[1];
    const void* W  = d_in[2];
    const void* aS = d_in[3];
    const void* aN = d_in[4];

    char* ws = (char*)d_ws;
    unsigned short* h_t = (unsigned short*)(ws + OFF_HT);
    float* att_s = (float*)(ws + OFF_ATTS);
    float* Eb    = (float*)(ws + OFF_E);
    float* E5b   = (float*)(ws + OFF_E5);
    unsigned long long* mask = (unsigned long long*)(ws + OFF_MASK);
    unsigned int* maxn_enc = (unsigned int*)(ws + OFF_MAXN);
    unsigned short* Xc = (unsigned short*)(ws + OFF_XC);
    unsigned short* Wc = (unsigned short*)(ws + OFF_WC);

    k_mask_conv<<<74240, 256, 0, stream>>>(A, X, W, mask, maxn_enc, Xc, Wc);
    k_gemm1<<<256, 256, 0, stream>>>(Xc, Wc, aS, aN, (const float*)A,
                                     h_t, att_s, Eb, E5b, maxn_enc);
    k_attn_av<<<2048, 128, 0, stream>>>((const unsigned int*)mask, h_t,
                                        att_s, Eb, E5b, maxn_enc,
                                        (const float*)A, d_out);
}

// Round 13
// 240.268 us; speedup vs baseline: 1.6317x; 1.0264x over previous
//
#include <hip/hip_runtime.h>

// GraphAttention: B=4, N=2048, F=256, H=8, F_=64; out [B, N, 512].
// 3 dispatches:
//  k_mask_conv: A->bitmask (+init maxn); X,W->bf16 (extra blocks).
//  k_gemm1    : h=X@W (MFMA, h_t transposed) + fused epilogue: att_s,
//               packed table Tb[j] = (bf16(exp(n))<<16)|bf16(exp(0.2n)),
//               per-bh max(att_n).
//  k_attn_av  : fused masked softmax @ h. Block = 128 thr = 2 waves; both
//               waves own the same 32 rows (2 A-frags), each covers a
//               1024-wide j-half -> 4096 waves (4/SIMD). SOFTWARE-PIPELINED:
//               iteration jc+1's table/mask/B-frag loads are issued while
//               computing jc (explicit next-regs) -- hides the ~200cyc L2
//               latency that serialized earlier rounds (VGPR 64, VALUBusy 31%).
//               Table-based P (no exp in hot loop): p = (E>exp(-s) ? k1*E
//               : k2*E5) * maskbit, c = leaky(s+maxn) >= row max.
//               l via ones-MFMA; trunc pack (bias cancels in l).
// Register budget: __launch_bounds__(128,4) -> 128 VGPR cap; pipelined live
// state ~115 regs. (256,6) once forced 40 VGPR -> spills -> 378MB HBM. Do
// not tighten the cap.
// Input dtype detected from A[0][0] (self-loop: fp32 word == 1.0f).

constexpr int GN  = 2048;
constexpr int GHF = 512;

using sh8    = __attribute__((ext_vector_type(8))) short;          // 8 bf16
using us4g   = __attribute__((ext_vector_type(4))) unsigned short;
using f32x4g = __attribute__((ext_vector_type(4))) float;
using u32x4g = __attribute__((ext_vector_type(4))) unsigned int;
using i32x4g = __attribute__((ext_vector_type(4))) int;

__device__ inline float gat_bf2f(unsigned short u) {
    union { unsigned int i; float f; } c; c.i = ((unsigned int)u) << 16; return c.f;
}
__device__ inline unsigned short gat_f2bf(float f) {
    union { float f; unsigned int i; } c; c.f = f;
    return (unsigned short)((c.i + 0x7fffu + ((c.i >> 16) & 1u)) >> 16); // RNE
}
__device__ inline int gat_isf32(const float* __restrict__ Aw) {
    float a = Aw[0];
    return (a == 0.0f) || (a == 1.0f);
}
__device__ inline unsigned int gat_enc(float f) {
    union { float f; unsigned int u; } c; c.f = f;
    return (c.u & 0x80000000u) ? ~c.u : (c.u | 0x80000000u);
}
__device__ inline float gat_dec(unsigned int e) {
    union { float f; unsigned int u; } c;
    c.u = (e & 0x80000000u) ? (e & 0x7fffffffu) : ~e;
    return c.f;
}

__global__ void GraphAttention_62981400429165_kernel() {}

// ---------------- workspace layout (bytes) ----------------
constexpr size_t OFF_HT   = 256;                       // h_t bf16       8 MB
constexpr size_t OFF_ATTS = OFF_HT   + 8388608;        // att_s f32    256 KB
constexpr size_t OFF_TB   = OFF_ATTS + 262144;         // packed E/E5  256 KB
constexpr size_t OFF_MASK = OFF_TB   + 262144;         // bitmask        2 MB
constexpr size_t OFF_MAXN = OFF_MASK + 2097152;        // 32 u32
constexpr size_t OFF_XC   = OFF_MAXN + 256;            // X bf16         4 MB
constexpr size_t OFF_WC   = OFF_XC   + 4194304;        // W bf16       256 KB

// --------------------------------------------------------------------------
// k_mask_conv: blocks 0..65535: A->mask (+block 0 inits maxn).
// 65536..73727: X->bf16. 73728..74239: W->bf16.
// --------------------------------------------------------------------------
__global__ __launch_bounds__(256) void k_mask_conv(const void* __restrict__ Araw,
                                                   const void* __restrict__ Xraw,
                                                   const void* __restrict__ Wraw,
                                                   unsigned long long* __restrict__ mask,
                                                   unsigned int* __restrict__ maxn_enc,
                                                   unsigned short* __restrict__ Xc,
                                                   unsigned short* __restrict__ Wc) {
    int tid = threadIdx.x, blk = blockIdx.x;
    int isf = gat_isf32((const float*)Araw);
    if (blk < 65536) {
        if (blk == 0 && tid < 32) maxn_enc[tid] = 0u;
        size_t idx = (size_t)blk * 256 + tid;
        int nz;
        if (isf) nz = (((const float*)Araw)[idx] != 0.0f);
        else     nz = (((const unsigned short*)Araw)[idx] != 0);
        unsigned long long bal = __ballot(nz);
        if ((tid & 63) == 0) mask[idx >> 6] = bal;
    } else if (blk < 73728) {
        int i = (blk - 65536) * 256 + tid;
        Xc[i] = isf ? gat_f2bf(((const float*)Xraw)[i]) : ((const unsigned short*)Xraw)[i];
    } else {
        int i = (blk - 73728) * 256 + tid;
        Wc[i] = isf ? gat_f2bf(((const float*)Wraw)[i]) : ((const unsigned short*)Wraw)[i];
    }
}

// --------------------------------------------------------------------------
// k_gemm1: h = X @ W per (b,h) + fused att epilogue (att_s, Tb, maxn).
// grid 256 (bh*8+it) x 256 (4 waves x 64 rows).
// --------------------------------------------------------------------------
constexpr int LDW = 264;
__global__ __launch_bounds__(256) void k_gemm1(const unsigned short* __restrict__ Xc,
                                               const unsigned short* __restrict__ Wc,
                                               const void* __restrict__ aSraw,
                                               const void* __restrict__ aNraw,
                                               const float* __restrict__ Aw,
                                               unsigned short* __restrict__ h_t,
                                               float* __restrict__ att_s,
                                               unsigned int* __restrict__ Tb,
                                               unsigned int* __restrict__ maxn_enc) {
    int blk = blockIdx.x;
    int bh = blk >> 3, it = blk & 7;
    int b = bh >> 3, hh = bh & 7;
    int isf = gat_isf32(Aw);
    __shared__ unsigned short Wt[64 * LDW];
    for (int idx = threadIdx.x; idx < 256 * 64; idx += 256) {
        int k = idx >> 6, col = idx & 63;
        Wt[col * LDW + k] = Wc[(hh * 256 + k) * 64 + col];
    }
    __syncthreads();
#if defined(__gfx950__)
    int wave = threadIdx.x >> 6, lane = threadIdx.x & 63;
    int lrw = lane & 15, quad = lane >> 4;
    int row0 = it * 256 + wave * 64;
    f32x4g acc[4][4] = {};
    for (int k0 = 0; k0 < 256; k0 += 32) {
        sh8 a[4], w[4];
        for (int rt = 0; rt < 4; rt++)
            a[rt] = *(const sh8*)&Xc[((size_t)(b * GN) + row0 + rt * 16 + lrw) * 256 + k0 + quad * 8];
        for (int ct = 0; ct < 4; ct++)
            w[ct] = *(const sh8*)&Wt[(ct * 16 + lrw) * LDW + k0 + quad * 8];
        for (int rt = 0; rt < 4; rt++)
            for (int ct = 0; ct < 4; ct++)
                acc[rt][ct] = __builtin_amdgcn_mfma_f32_16x16x32_bf16(a[rt], w[ct], acc[rt][ct], 0, 0, 0);
    }
    for (int rt = 0; rt < 4; rt++)
        for (int ct = 0; ct < 4; ct++) {
            int col = ct * 16 + lrw;
            int row = row0 + rt * 16 + quad * 4;
            us4g v;
            v[0] = gat_f2bf(acc[rt][ct][0]);
            v[1] = gat_f2bf(acc[rt][ct][1]);
            v[2] = gat_f2bf(acc[rt][ct][2]);
            v[3] = gat_f2bf(acc[rt][ct][3]);
            *(us4g*)&h_t[((size_t)(bh * 64 + col)) * GN + row] = v;
        }
    // ---- fused att epilogue: att_s, packed table, maxn ----
    float as_l[4], an_l[4];
    for (int ct = 0; ct < 4; ct++) {
        int col = hh * 64 + ct * 16 + lrw;
        as_l[ct] = isf ? ((const float*)aSraw)[col] : gat_bf2f(((const unsigned short*)aSraw)[col]);
        an_l[ct] = isf ? ((const float*)aNraw)[col] : gat_bf2f(((const unsigned short*)aNraw)[col]);
    }
    float wmax = -3e38f;
    for (int rt = 0; rt < 4; rt++)
        for (int r = 0; r < 4; r++) {
            float ps = acc[rt][0][r] * as_l[0] + acc[rt][1][r] * as_l[1]
                     + acc[rt][2][r] * as_l[2] + acc[rt][3][r] * as_l[3];
            float pn = acc[rt][0][r] * an_l[0] + acc[rt][1][r] * an_l[1]
                     + acc[rt][2][r] * an_l[2] + acc[rt][3][r] * an_l[3];
            for (int off = 1; off < 16; off <<= 1) {
                ps += __shfl_xor(ps, off);
                pn += __shfl_xor(pn, off);
            }
            int row = row0 + rt * 16 + quad * 4 + r;
            if (lrw == 0) {
                att_s[bh * GN + row] = ps;
                Tb[bh * GN + row] = ((unsigned int)gat_f2bf(__expf(pn)) << 16)
                                  | (unsigned int)gat_f2bf(__expf(0.2f * pn));
            }
            wmax = fmaxf(wmax, pn);
        }
    wmax = fmaxf(wmax, __shfl_xor(wmax, 16));
    wmax = fmaxf(wmax, __shfl_xor(wmax, 32));
    if (lane == 0) atomicMax(&maxn_enc[bh], gat_enc(wmax));
#else
    int row = it * 256 + threadIdx.x;
    float hrow[64];
    for (int col = 0; col < 64; col++) {
        float s = 0.f;
        for (int k = 0; k < 256; k++)
            s += gat_bf2f(Xc[((size_t)(b * GN) + row) * 256 + k]) * gat_bf2f(Wt[col * LDW + k]);
        hrow[col] = s;
        h_t[((size_t)(bh * 64 + col)) * GN + row] = gat_f2bf(s);
    }
    float ps = 0.f, pn = 0.f;
    for (int col = 0; col < 64; col++) {
        float as = isf ? ((const float*)aSraw)[hh * 64 + col] : gat_bf2f(((const unsigned short*)aSraw)[hh * 64 + col]);
        float an = isf ? ((const float*)aNraw)[hh * 64 + col] : gat_bf2f(((const unsigned short*)aNraw)[hh * 64 + col]);
        ps += hrow[col] * as;
        pn += hrow[col] * an;
    }
    att_s[bh * GN + row] = ps;
    Tb[bh * GN + row] = ((unsigned int)gat_f2bf(__expf(pn)) << 16)
                      | (unsigned int)gat_f2bf(__expf(0.2f * pn));
    atomicMax(&maxn_enc[bh], gat_enc(pn));
#endif
}

// --------------------------------------------------------------------------
// k_attn_av: out = relu( softmax(P) @ h ). grid 2048 (bh = blk&31 for XCD
// locality, it = blk>>5 -> 32 rows), 128 thr = 2 waves. Wave w handles
// j in [w*1024, w*1024+1024) for the SAME 32 rows (2 A-frags). Explicitly
// software-pipelined: next iteration's loads issued before current compute.
// Partials reduced through LDS at the end (no atomics).
// --------------------------------------------------------------------------
__global__ __launch_bounds__(128, 4) void k_attn_av(const unsigned int* __restrict__ mask32,
                                                    const unsigned short* __restrict__ h_t,
                                                    const float* __restrict__ att_s,
                                                    const unsigned int* __restrict__ Tb,
                                                    const unsigned int* __restrict__ maxn_enc,
                                                    const float* __restrict__ Aw,
                                                    void* __restrict__ outv) {
    int blk = blockIdx.x;
    int bh = blk & 31, it = blk >> 5;
    int b = bh >> 3, hh = bh & 7;
    int i0 = it * 32;
    int tid = threadIdx.x;
    int isf = gat_isf32(Aw);
    float maxn = gat_dec(maxn_enc[bh]);
    const unsigned int* Tp = Tb + (size_t)bh * GN;
    const unsigned short* hb = h_t + (size_t)bh * 64 * GN;
#if defined(__gfx950__)
    int wave = tid >> 6, lane = tid & 63, lrw = lane & 15, quad = lane >> 4;
    int kq = quad * 8;
    int j0 = wave * 1024;                            // this wave's j-half
    float k1[2], k2[2], T0[2];
    const unsigned int* mrf[2];
    for (int f = 0; f < 2; f++) {
        int row = i0 + f * 16 + lrw;
        float s = att_s[bh * GN + row];
        float z = s + maxn;
        float c = fmaxf(z, 0.2f * z);                // >= true row max
        k1[f] = __expf(s - c);
        k2[f] = __expf(0.2f * s - c);
        T0[f] = __expf(-s);
        mrf[f] = mask32 + ((size_t)(b * GN) + row) * 64 + wave * 32;
    }
    f32x4g acc[2][4] = {};
    f32x4g accl[2] = {};
    sh8 ones;
#pragma unroll
    for (int e = 0; e < 8; e++) ones[e] = (short)0x3f80;  // bf16 1.0

    // ---- prologue: load iteration 0 ----
    int jq0 = j0 + kq;
    u32x4g tA_c = *(const u32x4g*)&Tp[jq0];
    u32x4g tB_c = *(const u32x4g*)&Tp[jq0 + 4];
    unsigned int w0_c = mrf[0][0], w1_c = mrf[1][0];
    sh8 bf_c0 = *(const sh8*)&hb[((size_t)(0 * 16 + lrw)) * GN + jq0];
    sh8 bf_c1 = *(const sh8*)&hb[((size_t)(1 * 16 + lrw)) * GN + jq0];
    sh8 bf_c2 = *(const sh8*)&hb[((size_t)(2 * 16 + lrw)) * GN + jq0];
    sh8 bf_c3 = *(const sh8*)&hb[((size_t)(3 * 16 + lrw)) * GN + jq0];

#pragma unroll 1
    for (int jc = 0; jc < 32; jc++) {
        // ---- issue next iteration's loads (clamped; last iter redundant) ----
        int jn = jc < 31 ? jc + 1 : 31;
        int jqn = j0 + jn * 32 + kq;
        u32x4g tA_n = *(const u32x4g*)&Tp[jqn];
        u32x4g tB_n = *(const u32x4g*)&Tp[jqn + 4];
        unsigned int w0_n = mrf[0][jn], w1_n = mrf[1][jn];
        sh8 bf_n0 = *(const sh8*)&hb[((size_t)(0 * 16 + lrw)) * GN + jqn];
        sh8 bf_n1 = *(const sh8*)&hb[((size_t)(1 * 16 + lrw)) * GN + jqn];
        sh8 bf_n2 = *(const sh8*)&hb[((size_t)(2 * 16 + lrw)) * GN + jqn];
        sh8 bf_n3 = *(const sh8*)&hb[((size_t)(3 * 16 + lrw)) * GN + jqn];

        // ---- compute with current ----
        unsigned int w0 = w0_c >> kq, w1 = w1_c >> kq;
        unsigned int q0[8], q1[8];
#pragma unroll
        for (int e = 0; e < 8; e++) {
            unsigned int word = (e < 4) ? tA_c[e] : tB_c[e - 4];
            float Ev  = __uint_as_float(word & 0xffff0000u);
            float E5v = __uint_as_float(word << 16);
            float p0 = (Ev > T0[0]) ? (k1[0] * Ev) : (k2[0] * E5v);
            float p1 = (Ev > T0[1]) ? (k1[1] * Ev) : (k2[1] * E5v);
            p0 = ((w0 >> e) & 1u) ? p0 : 0.0f;
            p1 = ((w1 >> e) & 1u) ? p1 : 0.0f;
            q0[e] = __float_as_uint(p0);
            q1[e] = __float_as_uint(p1);
        }
        i32x4g f0, f1;
#pragma unroll
        for (int pp = 0; pp < 4; pp++) {             // trunc pack (bias cancels in l)
            f0[pp] = (int)((q0[2 * pp] >> 16) | (q0[2 * pp + 1] & 0xffff0000u));
            f1[pp] = (int)((q1[2 * pp] >> 16) | (q1[2 * pp + 1] & 0xffff0000u));
        }
        sh8 af0 = *(sh8*)&f0;
        sh8 af1 = *(sh8*)&f1;
        acc[0][0] = __builtin_amdgcn_mfma_f32_16x16x32_bf16(af0, bf_c0, acc[0][0], 0, 0, 0);
        acc[1][0] = __builtin_amdgcn_mfma_f32_16x16x32_bf16(af1, bf_c0, acc[1][0], 0, 0, 0);
        acc[0][1] = __builtin_amdgcn_mfma_f32_16x16x32_bf16(af0, bf_c1, acc[0][1], 0, 0, 0);
        acc[1][1] = __builtin_amdgcn_mfma_f32_16x16x32_bf16(af1, bf_c1, acc[1][1], 0, 0, 0);
        acc[0][2] = __builtin_amdgcn_mfma_f32_16x16x32_bf16(af0, bf_c2, acc[0][2], 0, 0, 0);
        acc[1][2] = __builtin_amdgcn_mfma_f32_16x16x32_bf16(af1, bf_c2, acc[1][2], 0, 0, 0);
        acc[0][3] = __builtin_amdgcn_mfma_f32_16x16x32_bf16(af0, bf_c3, acc[0][3], 0, 0, 0);
        acc[1][3] = __builtin_amdgcn_mfma_f32_16x16x32_bf16(af1, bf_c3, acc[1][3], 0, 0, 0);
        accl[0] = __builtin_amdgcn_mfma_f32_16x16x32_bf16(af0, ones, accl[0], 0, 0, 0);
        accl[1] = __builtin_amdgcn_mfma_f32_16x16x32_bf16(af1, ones, accl[1], 0, 0, 0);

        // ---- rotate ----
        tA_c = tA_n; tB_c = tB_n; w0_c = w0_n; w1_c = w1_n;
        bf_c0 = bf_n0; bf_c1 = bf_n1; bf_c2 = bf_n2; bf_c3 = bf_n3;
    }
    // ---- end-of-kernel reduction across the 2 j-half waves (LDS) ----
    __shared__ float lred[2 * 32];                   // [wave][row32]
    __shared__ float lsum[32];                       // 1/l per row
    __shared__ float red[2 * 2 * 16 * 17];           // [wave][f][r16][c16 pad17]
    if (lrw == 0) {
#pragma unroll
        for (int f = 0; f < 2; f++)
#pragma unroll
            for (int r = 0; r < 4; r++)
                lred[wave * 32 + f * 16 + quad * 4 + r] = accl[f][r];
    }
    __syncthreads();
    if (tid < 32)
        lsum[tid] = 1.0f / (lred[tid] + lred[32 + tid]);
    __syncthreads();
    for (int ct = 0; ct < 4; ct++) {
#pragma unroll
        for (int f = 0; f < 2; f++)
#pragma unroll
            for (int r = 0; r < 4; r++)
                red[wave * 544 + f * 272 + (quad * 4 + r) * 17 + lrw] = acc[f][ct][r];
        __syncthreads();
#pragma unroll
        for (int k = 0; k < 4; k++) {
            int pos = k * 128 + tid;                 // [0,512): f(1b) r16(4b) c16(4b)
            int f = pos >> 8, r16 = (pos >> 4) & 15, c16 = pos & 15;
            int bse = f * 272 + r16 * 17 + c16;
            float sum = red[bse] + red[bse + 544];
            float v = sum * lsum[f * 16 + r16];
            v = v > 0.f ? v : 0.f;
            int row = i0 + f * 16 + r16;
            size_t o = ((size_t)(b * GN) + row) * GHF + hh * 64 + ct * 16 + c16;
            if (isf) ((float*)outv)[o] = v;
            else     ((unsigned short*)outv)[o] = gat_f2bf(v);
        }
        __syncthreads();
    }
#else
    // correctness-only fallback: thread -> (row = tid>>2, 16-col quarter)
    int row = i0 + (tid >> 2), chh = (tid & 3) * 16;
    const unsigned int* mr = mask32 + ((size_t)(b * GN) + row) * 64;
    float s = att_s[bh * GN + row];
    float z = s + maxn;
    float c = fmaxf(z, 0.2f * z);
    float k1 = __expf(s - c), k2 = __expf(0.2f * s - c), T0 = __expf(-s);
    float l = 0.f;
    float accS[16] = {};
    for (int j = 0; j < GN; j++) {
        if (!((mr[j >> 5] >> (j & 31)) & 1u)) continue;
        unsigned int word = Tp[j];
        float Ev  = __uint_as_float(word & 0xffff0000u);
        float E5v = __uint_as_float(word << 16);
        float p = (Ev > T0) ? (k1 * Ev) : (k2 * E5v);
        union { float f; unsigned int u; } t; t.f = p; t.u &= 0xffff0000u;
        l += t.f;
        for (int cc = 0; cc < 16; cc++)
            accS[cc] += t.f * gat_bf2f(hb[(size_t)(chh + cc) * GN + j]);
    }
    float li = 1.0f / l;
    for (int cc = 0; cc < 16; cc++) {
        float v = accS[cc] * li; v = v > 0.f ? v : 0.f;
        size_t oi = ((size_t)(b * GN) + row) * GHF + hh * 64 + chh + cc;
        if (isf) ((float*)outv)[oi] = v;
        else     ((unsigned short*)outv)[oi] = gat_f2bf(v);
    }
#endif
}

// --------------------------------------------------------------------------
extern "C" void kernel_launch(void* const* d_in, const int* in_sizes, int n_in,
                              void* d_out, int out_size, void* d_ws, size_t ws_size,
                              hipStream_t stream) {
    const void* X  = d_in[0];
    const void* A  = d_in[1];
    const void* W  = d_in[2];
    const void* aS = d_in[3];
    const void* aN = d_in[4];

    char* ws = (char*)d_ws;
    unsigned short* h_t = (unsigned short*)(ws + OFF_HT);
    float* att_s = (float*)(ws + OFF_ATTS);
    unsigned int* Tb = (unsigned int*)(ws + OFF_TB);
    unsigned long long* mask = (unsigned long long*)(ws + OFF_MASK);
    unsigned int* maxn_enc = (unsigned int*)(ws + OFF_MAXN);
    unsigned short* Xc = (unsigned short*)(ws + OFF_XC);
    unsigned short* Wc = (unsigned short*)(ws + OFF_WC);

    k_mask_conv<<<74240, 256, 0, stream>>>(A, X, W, mask, maxn_enc, Xc, Wc);
    k_gemm1<<<256, 256, 0, stream>>>(Xc, Wc, aS, aN, (const float*)A,
                                     h_t, att_s, Tb, maxn_enc);
    k_attn_av<<<2048, 128, 0, stream>>>((const unsigned int*)mask, h_t,
                                        att_s, Tb, maxn_enc,
                                        (const float*)A, d_out);
}

// Round 14
// 199.935 us; speedup vs baseline: 1.9608x; 1.2017x over previous
//
#include <hip/hip_runtime.h>

// GraphAttention: B=4, N=2048, F=256, H=8, F_=64; out [B, N, 512].
// 3 dispatches:
//  k_mask_conv: A->bitmask (+init maxn); X,W->bf16 (extra blocks).
//  k_gemm1    : h=X@W (MFMA) + att epilogue (att_s, packed exp table Tb,
//               per-bh max(att_n)) + LDS repack of h into MFMA-FRAGMENT
//               layout hswz[bh][jc][ct][lane][8] so k_attn_av's B-loads are
//               lane-linear (16B/lane contiguous).
//  k_attn_av  : fused masked softmax @ h. Block = 128 thr = 2 waves; both
//               waves own the same 32 rows (2 A-frags), each a 1024-wide
//               j-half -> 4096 waves (4/SIMD); LDS end-reduction, no atomics.
//               Table-based P (no exp in hot loop).
// History notes: r9 global-atomic j-split -> 425MB HBM (never); r11
// (256,6) forced 40 VGPR -> spills -> 378MB (keep cap >=128); r8-r13 all
// ~106-111us regardless of occupancy -> bound by 16-row gathered B-loads;
// this round fixes the layout.
// Input dtype detected from A[0][0] (self-loop: fp32 word == 1.0f).

constexpr int GN  = 2048;
constexpr int GHF = 512;

using sh8    = __attribute__((ext_vector_type(8))) short;          // 8 bf16
using us4g   = __attribute__((ext_vector_type(4))) unsigned short;
using f32x4g = __attribute__((ext_vector_type(4))) float;
using u32x4g = __attribute__((ext_vector_type(4))) unsigned int;
using i32x4g = __attribute__((ext_vector_type(4))) int;

__device__ inline float gat_bf2f(unsigned short u) {
    union { unsigned int i; float f; } c; c.i = ((unsigned int)u) << 16; return c.f;
}
__device__ inline unsigned short gat_f2bf(float f) {
    union { float f; unsigned int i; } c; c.f = f;
    return (unsigned short)((c.i + 0x7fffu + ((c.i >> 16) & 1u)) >> 16); // RNE
}
__device__ inline int gat_isf32(const float* __restrict__ Aw) {
    float a = Aw[0];
    return (a == 0.0f) || (a == 1.0f);
}
__device__ inline unsigned int gat_enc(float f) {
    union { float f; unsigned int u; } c; c.f = f;
    return (c.u & 0x80000000u) ? ~c.u : (c.u | 0x80000000u);
}
__device__ inline float gat_dec(unsigned int e) {
    union { float f; unsigned int u; } c;
    c.u = (e & 0x80000000u) ? (e & 0x7fffffffu) : ~e;
    return c.f;
}
// fragment-layout accessor (scalar, for fallback paths):
// h[o][j] of head-slice -> flat elem index in hswz (per-bh base excluded)
__device__ inline size_t gat_hswz_idx(int o, int j) {
    int jc = j >> 5, quad = (j >> 3) & 3, e = j & 7;
    int lane = quad * 16 + (o & 15);
    return (((size_t)(jc * 4 + (o >> 4))) * 64 + lane) * 8 + e;
}

__global__ void GraphAttention_62981400429165_kernel() {}

// ---------------- workspace layout (bytes) ----------------
constexpr size_t OFF_HS   = 256;                       // hswz bf16      8 MB
constexpr size_t OFF_ATTS = OFF_HS   + 8388608;        // att_s f32    256 KB
constexpr size_t OFF_TB   = OFF_ATTS + 262144;         // packed E/E5  256 KB
constexpr size_t OFF_MASK = OFF_TB   + 262144;         // bitmask        2 MB
constexpr size_t OFF_MAXN = OFF_MASK + 2097152;        // 32 u32
constexpr size_t OFF_XC   = OFF_MAXN + 256;            // X bf16         4 MB
constexpr size_t OFF_WC   = OFF_XC   + 4194304;        // W bf16       256 KB

// --------------------------------------------------------------------------
// k_mask_conv: blocks 0..65535: A->mask (+block 0 inits maxn).
// 65536..73727: X->bf16. 73728..74239: W->bf16.
// --------------------------------------------------------------------------
__global__ __launch_bounds__(256) void k_mask_conv(const void* __restrict__ Araw,
                                                   const void* __restrict__ Xraw,
                                                   const void* __restrict__ Wraw,
                                                   unsigned long long* __restrict__ mask,
                                                   unsigned int* __restrict__ maxn_enc,
                                                   unsigned short* __restrict__ Xc,
                                                   unsigned short* __restrict__ Wc) {
    int tid = threadIdx.x, blk = blockIdx.x;
    int isf = gat_isf32((const float*)Araw);
    if (blk < 65536) {
        if (blk == 0 && tid < 32) maxn_enc[tid] = 0u;
        size_t idx = (size_t)blk * 256 + tid;
        int nz;
        if (isf) nz = (((const float*)Araw)[idx] != 0.0f);
        else     nz = (((const unsigned short*)Araw)[idx] != 0);
        unsigned long long bal = __ballot(nz);
        if ((tid & 63) == 0) mask[idx >> 6] = bal;
    } else if (blk < 73728) {
        int i = (blk - 65536) * 256 + tid;
        Xc[i] = isf ? gat_f2bf(((const float*)Xraw)[i]) : ((const unsigned short*)Xraw)[i];
    } else {
        int i = (blk - 73728) * 256 + tid;
        Wc[i] = isf ? gat_f2bf(((const float*)Wraw)[i]) : ((const unsigned short*)Wraw)[i];
    }
}

// --------------------------------------------------------------------------
// k_gemm1: h = X @ W per (b,h) + att epilogue + fragment-layout repack.
// grid 256 (bh*8+it) x 256 (4 waves x 64 rows).
// --------------------------------------------------------------------------
constexpr int LDW = 264;
__global__ __launch_bounds__(256) void k_gemm1(const unsigned short* __restrict__ Xc,
                                               const unsigned short* __restrict__ Wc,
                                               const void* __restrict__ aSraw,
                                               const void* __restrict__ aNraw,
                                               const float* __restrict__ Aw,
                                               unsigned short* __restrict__ hswz,
                                               float* __restrict__ att_s,
                                               unsigned int* __restrict__ Tb,
                                               unsigned int* __restrict__ maxn_enc) {
    int blk = blockIdx.x;
    int bh = blk >> 3, it = blk & 7;
    int b = bh >> 3, hh = bh & 7;
    int isf = gat_isf32(Aw);
    __shared__ unsigned short Wt[64 * LDW];          // reused as CtT after K-loop
    for (int idx = threadIdx.x; idx < 256 * 64; idx += 256) {
        int k = idx >> 6, col = idx & 63;
        Wt[col * LDW + k] = Wc[(hh * 256 + k) * 64 + col];
    }
    __syncthreads();
#if defined(__gfx950__)
    int wave = threadIdx.x >> 6, lane = threadIdx.x & 63;
    int lrw = lane & 15, quad = lane >> 4;
    int row0 = it * 256 + wave * 64;
    f32x4g acc[4][4] = {};
    for (int k0 = 0; k0 < 256; k0 += 32) {
        sh8 a[4], w[4];
        for (int rt = 0; rt < 4; rt++)
            a[rt] = *(const sh8*)&Xc[((size_t)(b * GN) + row0 + rt * 16 + lrw) * 256 + k0 + quad * 8];
        for (int ct = 0; ct < 4; ct++)
            w[ct] = *(const sh8*)&Wt[(ct * 16 + lrw) * LDW + k0 + quad * 8];
        for (int rt = 0; rt < 4; rt++)
            for (int ct = 0; ct < 4; ct++)
                acc[rt][ct] = __builtin_amdgcn_mfma_f32_16x16x32_bf16(a[rt], w[ct], acc[rt][ct], 0, 0, 0);
    }
    // ---- att epilogue (register-only): att_s, packed table, maxn ----
    float as_l[4], an_l[4];
    for (int ct = 0; ct < 4; ct++) {
        int col = hh * 64 + ct * 16 + lrw;
        as_l[ct] = isf ? ((const float*)aSraw)[col] : gat_bf2f(((const unsigned short*)aSraw)[col]);
        an_l[ct] = isf ? ((const float*)aNraw)[col] : gat_bf2f(((const unsigned short*)aNraw)[col]);
    }
    float wmax = -3e38f;
    for (int rt = 0; rt < 4; rt++)
        for (int r = 0; r < 4; r++) {
            float ps = acc[rt][0][r] * as_l[0] + acc[rt][1][r] * as_l[1]
                     + acc[rt][2][r] * as_l[2] + acc[rt][3][r] * as_l[3];
            float pn = acc[rt][0][r] * an_l[0] + acc[rt][1][r] * an_l[1]
                     + acc[rt][2][r] * an_l[2] + acc[rt][3][r] * an_l[3];
            for (int off = 1; off < 16; off <<= 1) {
                ps += __shfl_xor(ps, off);
                pn += __shfl_xor(pn, off);
            }
            int row = row0 + rt * 16 + quad * 4 + r;
            if (lrw == 0) {
                att_s[bh * GN + row] = ps;
                Tb[bh * GN + row] = ((unsigned int)gat_f2bf(__expf(pn)) << 16)
                                  | (unsigned int)gat_f2bf(__expf(0.2f * pn));
            }
            wmax = fmaxf(wmax, pn);
        }
    wmax = fmaxf(wmax, __shfl_xor(wmax, 16));
    wmax = fmaxf(wmax, __shfl_xor(wmax, 32));
    if (lane == 0) atomicMax(&maxn_enc[bh], gat_enc(wmax));
    // ---- repack: acc -> LDS CtT[o][nloc] -> hswz fragment layout ----
    __syncthreads();                                  // Wt reads done; reuse as CtT
    unsigned short* CtT = Wt;                         // [o][nloc], stride LDW
    for (int rt = 0; rt < 4; rt++)
        for (int ct = 0; ct < 4; ct++) {
            int o = ct * 16 + lrw;
            int nloc = wave * 64 + rt * 16 + quad * 4;
            us4g v;
            v[0] = gat_f2bf(acc[rt][ct][0]);
            v[1] = gat_f2bf(acc[rt][ct][1]);
            v[2] = gat_f2bf(acc[rt][ct][2]);
            v[3] = gat_f2bf(acc[rt][ct][3]);
            *(us4g*)&CtT[o * LDW + nloc] = v;
        }
    __syncthreads();
    // 2048 fragment-lane items (8 jc_loc x 4 ct x 64 lane), 8 per thread
    for (int k = 0; k < 8; k++) {
        int id = k * 256 + threadIdx.x;
        int ln = id & 63, t = id >> 6;               // t in [0,32)
        int jc_loc = t >> 2, ct = t & 3;
        int lrw2 = ln & 15, quad2 = ln >> 4;
        int o = ct * 16 + lrw2;
        int nloc = jc_loc * 32 + quad2 * 8;
        sh8 v = *(const sh8*)&CtT[o * LDW + nloc];
        size_t dst = ((((size_t)(bh * 64 + it * 8 + jc_loc)) * 4 + ct) * 64 + ln) * 8;
        *(sh8*)&hswz[dst] = v;
    }
#else
    // fallback: thread per row, scalar
    int row = it * 256 + threadIdx.x;
    float hrow[64];
    for (int col = 0; col < 64; col++) {
        float s = 0.f;
        for (int k = 0; k < 256; k++)
            s += gat_bf2f(Xc[((size_t)(b * GN) + row) * 256 + k]) * gat_bf2f(Wt[col * LDW + k]);
        hrow[col] = s;
        hswz[(size_t)bh * 64 * GN * 2 / 2 * 0 + 0] = hswz[0]; // no-op placeholder
    }
    for (int col = 0; col < 64; col++) {
        size_t base = (size_t)bh * 64 * GN;          // elems per bh slice = 64*2048
        hswz[base + gat_hswz_idx(col, row)] = gat_f2bf(hrow[col]);
    }
    float ps = 0.f, pn = 0.f;
    for (int col = 0; col < 64; col++) {
        float as = isf ? ((const float*)aSraw)[hh * 64 + col] : gat_bf2f(((const unsigned short*)aSraw)[hh * 64 + col]);
        float an = isf ? ((const float*)aNraw)[hh * 64 + col] : gat_bf2f(((const unsigned short*)aNraw)[hh * 64 + col]);
        ps += hrow[col] * as;
        pn += hrow[col] * an;
    }
    att_s[bh * GN + row] = ps;
    Tb[bh * GN + row] = ((unsigned int)gat_f2bf(__expf(pn)) << 16)
                      | (unsigned int)gat_f2bf(__expf(0.2f * pn));
    atomicMax(&maxn_enc[bh], gat_enc(pn));
#endif
}

// --------------------------------------------------------------------------
// k_attn_av: out = relu( softmax(P) @ h ). grid 2048 (bh = blk&31 for XCD
// locality, it = blk>>5 -> 32 rows), 128 thr = 2 waves; wave w covers j in
// [w*1024, +1024) for the SAME 32 rows. B-frags are lane-linear 16B loads
// from hswz. LDS end-reduction, no atomics. Table-based P.
// --------------------------------------------------------------------------
__global__ __launch_bounds__(128, 4) void k_attn_av(const unsigned int* __restrict__ mask32,
                                                    const unsigned short* __restrict__ hswz,
                                                    const float* __restrict__ att_s,
                                                    const unsigned int* __restrict__ Tb,
                                                    const unsigned int* __restrict__ maxn_enc,
                                                    const float* __restrict__ Aw,
                                                    void* __restrict__ outv) {
    int blk = blockIdx.x;
    int bh = blk & 31, it = blk >> 5;
    int b = bh >> 3, hh = bh & 7;
    int i0 = it * 32;
    int tid = threadIdx.x;
    int isf = gat_isf32(Aw);
    float maxn = gat_dec(maxn_enc[bh]);
    const unsigned int* Tp = Tb + (size_t)bh * GN;
#if defined(__gfx950__)
    int wave = tid >> 6, lane = tid & 63, lrw = lane & 15, quad = lane >> 4;
    int kq = quad * 8;
    int j0 = wave * 1024;                            // this wave's j-half
    // per-wave fragment base: jc group wave*32, lane-linear
    const unsigned short* hs = hswz + ((size_t)(bh * 64) + wave * 32) * 2048 + lane * 8;
    float k1[2], k2[2], T0[2];
    const unsigned int* mrf[2];
    for (int f = 0; f < 2; f++) {
        int row = i0 + f * 16 + lrw;
        float s = att_s[bh * GN + row];
        float z = s + maxn;
        float c = fmaxf(z, 0.2f * z);                // >= true row max
        k1[f] = __expf(s - c);
        k2[f] = __expf(0.2f * s - c);
        T0[f] = __expf(-s);
        mrf[f] = mask32 + ((size_t)(b * GN) + row) * 64 + wave * 32;
    }
    f32x4g acc[2][4] = {};
    f32x4g accl[2] = {};
    sh8 ones;
#pragma unroll
    for (int e = 0; e < 8; e++) ones[e] = (short)0x3f80;  // bf16 1.0

#pragma unroll 1
    for (int jg = 0; jg < 8; jg++) {                 // 8 groups x 4 jc
        u32x4g m0 = *(const u32x4g*)&mrf[0][jg * 4];
        u32x4g m1 = *(const u32x4g*)&mrf[1][jg * 4];
#pragma unroll
        for (int sj = 0; sj < 4; sj++) {
            int jc = jg * 4 + sj;
            int jq = j0 + jc * 32 + kq;
            u32x4g tA = *(const u32x4g*)&Tp[jq];
            u32x4g tB = *(const u32x4g*)&Tp[jq + 4];
            const unsigned short* hp = hs + jc * 2048;
            sh8 b0 = *(const sh8*)&hp[0];            // ct=0 (lane-linear 16B)
            sh8 b1 = *(const sh8*)&hp[512];          // ct=1
            sh8 b2 = *(const sh8*)&hp[1024];         // ct=2
            sh8 b3 = *(const sh8*)&hp[1536];         // ct=3
            unsigned int w0 = m0[sj] >> kq;
            unsigned int w1 = m1[sj] >> kq;
            unsigned int q0[8], q1[8];
#pragma unroll
            for (int e = 0; e < 8; e++) {
                unsigned int word = (e < 4) ? tA[e] : tB[e - 4];
                float Ev  = __uint_as_float(word & 0xffff0000u);
                float E5v = __uint_as_float(word << 16);
                float p0 = (Ev > T0[0]) ? (k1[0] * Ev) : (k2[0] * E5v);
                float p1 = (Ev > T0[1]) ? (k1[1] * Ev) : (k2[1] * E5v);
                p0 = ((w0 >> e) & 1u) ? p0 : 0.0f;
                p1 = ((w1 >> e) & 1u) ? p1 : 0.0f;
                q0[e] = __float_as_uint(p0);
                q1[e] = __float_as_uint(p1);
            }
            i32x4g f0, f1;
#pragma unroll
            for (int pp = 0; pp < 4; pp++) {         // trunc pack (bias cancels in l)
                f0[pp] = (int)((q0[2 * pp] >> 16) | (q0[2 * pp + 1] & 0xffff0000u));
                f1[pp] = (int)((q1[2 * pp] >> 16) | (q1[2 * pp + 1] & 0xffff0000u));
            }
            sh8 af0 = *(sh8*)&f0;
            sh8 af1 = *(sh8*)&f1;
            acc[0][0] = __builtin_amdgcn_mfma_f32_16x16x32_bf16(af0, b0, acc[0][0], 0, 0, 0);
            acc[1][0] = __builtin_amdgcn_mfma_f32_16x16x32_bf16(af1, b0, acc[1][0], 0, 0, 0);
            acc[0][1] = __builtin_amdgcn_mfma_f32_16x16x32_bf16(af0, b1, acc[0][1], 0, 0, 0);
            acc[1][1] = __builtin_amdgcn_mfma_f32_16x16x32_bf16(af1, b1, acc[1][1], 0, 0, 0);
            acc[0][2] = __builtin_amdgcn_mfma_f32_16x16x32_bf16(af0, b2, acc[0][2], 0, 0, 0);
            acc[1][2] = __builtin_amdgcn_mfma_f32_16x16x32_bf16(af1, b2, acc[1][2], 0, 0, 0);
            acc[0][3] = __builtin_amdgcn_mfma_f32_16x16x32_bf16(af0, b3, acc[0][3], 0, 0, 0);
            acc[1][3] = __builtin_amdgcn_mfma_f32_16x16x32_bf16(af1, b3, acc[1][3], 0, 0, 0);
            accl[0] = __builtin_amdgcn_mfma_f32_16x16x32_bf16(af0, ones, accl[0], 0, 0, 0);
            accl[1] = __builtin_amdgcn_mfma_f32_16x16x32_bf16(af1, ones, accl[1], 0, 0, 0);
        }
    }
    // ---- end-of-kernel reduction across the 2 j-half waves (LDS) ----
    __shared__ float lred[2 * 32];                   // [wave][row32]
    __shared__ float lsum[32];                       // 1/l per row
    __shared__ float red[2 * 2 * 16 * 17];           // [wave][f][r16][c16 pad17]
    if (lrw == 0) {
#pragma unroll
        for (int f = 0; f < 2; f++)
#pragma unroll
            for (int r = 0; r < 4; r++)
                lred[wave * 32 + f * 16 + quad * 4 + r] = accl[f][r];
    }
    __syncthreads();
    if (tid < 32)
        lsum[tid] = 1.0f / (lred[tid] + lred[32 + tid]);
    __syncthreads();
    for (int ct = 0; ct < 4; ct++) {
#pragma unroll
        for (int f = 0; f < 2; f++)
#pragma unroll
            for (int r = 0; r < 4; r++)
                red[wave * 544 + f * 272 + (quad * 4 + r) * 17 + lrw] = acc[f][ct][r];
        __syncthreads();
#pragma unroll
        for (int k = 0; k < 4; k++) {
            int pos = k * 128 + tid;                 // [0,512): f(1b) r16(4b) c16(4b)
            int f = pos >> 8, r16 = (pos >> 4) & 15, c16 = pos & 15;
            int bse = f * 272 + r16 * 17 + c16;
            float sum = red[bse] + red[bse + 544];
            float v = sum * lsum[f * 16 + r16];
            v = v > 0.f ? v : 0.f;
            int row = i0 + f * 16 + r16;
            size_t o = ((size_t)(b * GN) + row) * GHF + hh * 64 + ct * 16 + c16;
            if (isf) ((float*)outv)[o] = v;
            else     ((unsigned short*)outv)[o] = gat_f2bf(v);
        }
        __syncthreads();
    }
#else
    // correctness-only fallback: thread -> (row = tid>>2, 16-col quarter)
    int row = i0 + (tid >> 2), chh = (tid & 3) * 16;
    const unsigned short* hbb = hswz + (size_t)(bh * 64) * GN;  // per-bh slice
    const unsigned int* mr = mask32 + ((size_t)(b * GN) + row) * 64;
    float s = att_s[bh * GN + row];
    float z = s + maxn;
    float c = fmaxf(z, 0.2f * z);
    float k1 = __expf(s - c), k2 = __expf(0.2f * s - c), T0 = __expf(-s);
    float l = 0.f;
    float accS[16] = {};
    for (int j = 0; j < GN; j++) {
        if (!((mr[j >> 5] >> (j & 31)) & 1u)) continue;
        unsigned int word = Tp[j];
        float Ev  = __uint_as_float(word & 0xffff0000u);
        float E5v = __uint_as_float(word << 16);
        float p = (Ev > T0) ? (k1 * Ev) : (k2 * E5v);
        union { float f; unsigned int u; } t; t.f = p; t.u &= 0xffff0000u;
        l += t.f;
        for (int cc = 0; cc < 16; cc++)
            accS[cc] += t.f * gat_bf2f(hbb[gat_hswz_idx(chh + cc, j)]);
    }
    float li = 1.0f / l;
    for (int cc = 0; cc < 16; cc++) {
        float v = accS[cc] * li; v = v > 0.f ? v : 0.f;
        size_t oi = ((size_t)(b * GN) + row) * GHF + hh * 64 + chh + cc;
        if (isf) ((float*)outv)[oi] = v;
        else     ((unsigned short*)outv)[oi] = gat_f2bf(v);
    }
#endif
}

// --------------------------------------------------------------------------
extern "C" void kernel_launch(void* const* d_in, const int* in_sizes, int n_in,
                              void* d_out, int out_size, void* d_ws, size_t ws_size,
                              hipStream_t stream) {
    const void* X  = d_in[0];
    const void* A  = d_in[1];
    const void* W  = d_in[2];
    const void* aS = d_in[3];
    const void* aN = d_in[4];

    char* ws = (char*)d_ws;
    unsigned short* hswz = (unsigned short*)(ws + OFF_HS);
    float* att_s = (float*)(ws + OFF_ATTS);
    unsigned int* Tb = (unsigned int*)(ws + OFF_TB);
    unsigned long long* mask = (unsigned long long*)(ws + OFF_MASK);
    unsigned int* maxn_enc = (unsigned int*)(ws + OFF_MAXN);
    unsigned short* Xc = (unsigned short*)(ws + OFF_XC);
    unsigned short* Wc = (unsigned short*)(ws + OFF_WC);

    k_mask_conv<<<74240, 256, 0, stream>>>(A, X, W, mask, maxn_enc, Xc, Wc);
    k_gemm1<<<256, 256, 0, stream>>>(Xc, Wc, aS, aN, (const float*)A,
                                     hswz, att_s, Tb, maxn_enc);
    k_attn_av<<<2048, 128, 0, stream>>>((const unsigned int*)mask, hswz,
                                        att_s, Tb, maxn_enc,
                                        (const float*)A, d_out);
}